// Round 7
// baseline (132.304 us; speedup 1.0000x reference)
//
#include <hip/hip_runtime.h>
#include <cstdint>

// Transformer block: B=16, S=1024, E=256, H=4, D=64. fp32 in/out, bf16 compute.
// T = B*S = 16384 tokens.
//
//  0. Wt    = transpose+bf16(all weights)      -> ws
//  1. h     = LN1(x)                    bf16   -> bufA
//  2. qkv   = h @ qkv_w + qkv_b         bf16   -> qk_buf [T,512] + vt_buf [BH,64,1024]
//  3. o     = causal_attn(qk, vt)       bf16   -> bufA   (1024 balanced blocks, dbuf)
//  4. x1,h2 = fused(x + o@out_w+b, LN2) f32,bf16 -> d_out, bufA
//  5. h3    = relu(h2 @ fc_w + b)       bf16   -> bufB (overlays qk/vt)
//  6. out   = x1 + h3 @ proj_w + b      fp32   -> d_out
// All GEMMs: 2-phase double-buffered staging (stage k+1 before compute k).

using f32x4 = __attribute__((ext_vector_type(4))) float;
using s16x8 = __attribute__((ext_vector_type(8))) short;
using s16x4 = __attribute__((ext_vector_type(4))) short;

__device__ inline short f2bf(float f) {
    union { float f; unsigned u; } v{f};
    unsigned r = (v.u + 0x7FFFu + ((v.u >> 16) & 1u)) >> 16;   // RNE
    return (short)r;
}

__device__ inline int cvt_pk_bf16(float lo, float hi) {
    int d;
    asm("v_cvt_pk_bf16_f32 %0, %1, %2" : "=v"(d) : "v"(lo), "v"(hi));
    return d;
}
__device__ inline void swap32(int& a, int& b) {
    asm("v_permlane32_swap_b32 %0, %1" : "+v"(a), "+v"(b));
}
__device__ inline void swap16(int& a, int& b) {
    asm("v_permlane16_swap_b32 %0, %1" : "+v"(a), "+v"(b));
}

__device__ inline void gload16(const void* g, void* l) {
    __builtin_amdgcn_global_load_lds(
        (const __attribute__((address_space(1))) void*)g,
        (__attribute__((address_space(3))) void*)l, 16, 0, 0);
}

// ------------------------------------------------ weight fp32->bf16 transpose
__global__ __launch_bounds__(256) void wconv_all_kernel(
    const float* __restrict__ qkv_w, const float* __restrict__ out_w,
    const float* __restrict__ fc_w,  const float* __restrict__ proj_w,
    short* __restrict__ wt_qkv, short* __restrict__ wt_out,
    short* __restrict__ wt_fc,  short* __restrict__ wt_proj)
{
    __shared__ short T[64][65];
    int id = blockIdx.x;
    const float* W; short* Wt; int K, N, nt, kt;
    if (id < 48)       { W = qkv_w;  Wt = wt_qkv;  K = 256;  N = 768;  nt = id % 12;        kt = id / 12; }
    else if (id < 64)  { W = out_w;  Wt = wt_out;  K = 256;  N = 256;  nt = (id - 48) & 3;  kt = (id - 48) >> 2; }
    else if (id < 128) { W = fc_w;   Wt = wt_fc;   K = 256;  N = 1024; nt = (id - 64) & 15; kt = (id - 64) >> 4; }
    else               { W = proj_w; Wt = wt_proj; K = 1024; N = 256;  nt = (id - 128) & 3; kt = (id - 128) >> 2; }
    int n0 = nt * 64, k0 = kt * 64;

    int tid = threadIdx.x;
    int r  = tid >> 2;
    int c  = (tid & 3) << 4;

    const float* src = W + (size_t)(k0 + r) * N + n0 + c;
#pragma unroll
    for (int u = 0; u < 4; ++u) {
        float4 v = *reinterpret_cast<const float4*>(src + u * 4);
        T[r][c + u * 4 + 0] = f2bf(v.x);
        T[r][c + u * 4 + 1] = f2bf(v.y);
        T[r][c + u * 4 + 2] = f2bf(v.z);
        T[r][c + u * 4 + 3] = f2bf(v.w);
    }
    __syncthreads();
    s16x8 o0, o1;
#pragma unroll
    for (int j = 0; j < 8; ++j) { o0[j] = T[c + j][r]; o1[j] = T[c + 8 + j][r]; }
    short* dst = Wt + (size_t)(n0 + r) * K + k0 + c;
    *reinterpret_cast<s16x8*>(dst)     = o0;
    *reinterpret_cast<s16x8*>(dst + 8) = o1;
}

// ---------------------------------------------------------------- LayerNorm
__global__ __launch_bounds__(256) void ln_kernel(const float* __restrict__ x,
                                                 const float* __restrict__ gamma,
                                                 const float* __restrict__ beta,
                                                 short* __restrict__ out)
{
    int tid  = threadIdx.x;
    int lane = tid & 63;
    int row  = blockIdx.x * 4 + (tid >> 6);
    const float* xr = x + (size_t)row * 256;
    float4 v = *reinterpret_cast<const float4*>(xr + lane * 4);

    float s = v.x + v.y + v.z + v.w;
#pragma unroll
    for (int o = 32; o >= 1; o >>= 1) s += __shfl_xor(s, o);
    float mu = s * (1.0f / 256.0f);

    float dx = v.x - mu, dy = v.y - mu, dz = v.z - mu, dw = v.w - mu;
    float q = dx * dx + dy * dy + dz * dz + dw * dw;
#pragma unroll
    for (int o = 32; o >= 1; o >>= 1) q += __shfl_xor(q, o);
    float rstd = rsqrtf(q * (1.0f / 256.0f) + 1e-5f);

    float4 gv = *reinterpret_cast<const float4*>(gamma + lane * 4);
    float4 bv = *reinterpret_cast<const float4*>(beta + lane * 4);
    s16x4 ov;
    ov[0] = f2bf(dx * rstd * gv.x + bv.x);
    ov[1] = f2bf(dy * rstd * gv.y + bv.y);
    ov[2] = f2bf(dz * rstd * gv.z + bv.z);
    ov[3] = f2bf(dw * rstd * gv.w + bv.w);
    *reinterpret_cast<s16x4*>(out + (size_t)row * 256 + lane * 4) = ov;
}

// ---------------------------------------------------------------- MFMA GEMM
// 2-phase double-buffered: stage(k+1) issued BEFORE compute(k), so the
// barrier's vmcnt drain overlaps the MFMA phase (T3-minimum).
template <int RELU, int RES, int OBF16, int BM, int QKV>
__global__ __launch_bounds__(256) void mgemm_kernel(const short* __restrict__ A,
                                                    const short* __restrict__ Bt,
                                                    const float* __restrict__ bias,
                                                    const float* __restrict__ R,
                                                    void* __restrict__ Cv,
                                                    short* __restrict__ vt,
                                                    int N, int K)
{
    constexpr int MI  = BM / 32;
    constexpr int ASZ = BM * 64;
    constexpr int BSZ = 128 * 64;
    __shared__ short As[2 * ASZ];
    __shared__ short Bs[2 * BSZ];

    int tid = threadIdx.x;
    int l   = tid & 63;
    int w   = tid >> 6;
    int lr  = l & 15;
    int lk8 = (l >> 4) << 3;
    int r4  = (l >> 4) << 2;
    int wr  = w >> 1, wc = w & 1;
    int bn  = blockIdx.x * 128, bm = blockIdx.y * BM;

    int scolS = ((l & 7) << 3) ^ ((l >> 3) << 3);
    int srowA = w * (BM / 4) + (l >> 3);
    int srowB = (w << 5) + (l >> 3);
    const short* pa = A  + (size_t)(bm + srowA) * K + scolS;
    const short* pb = Bt + (size_t)(bn + srowB) * K + scolS;
    short* dstA = As + w * (BM / 4) * 64;
    short* dstB = Bs + (w << 11);

    f32x4 acc[MI][4];
#pragma unroll
    for (int mi = 0; mi < MI; ++mi)
#pragma unroll
        for (int ni = 0; ni < 4; ++ni) acc[mi][ni] = (f32x4){0.f, 0.f, 0.f, 0.f};

    int swz = (lr & 7) << 3;

    // prologue: stage k0=0 into half 0
#pragma unroll
    for (int i = 0; i < BM / 32; ++i)
        gload16(pa + (size_t)(i * 8) * K, dstA + (i << 9));
#pragma unroll
    for (int i = 0; i < 4; ++i)
        gload16(pb + (size_t)(i * 8) * K, dstB + (i << 9));
    __syncthreads();

    int cur = 0;
    for (int k0 = 0; k0 < K; k0 += 64) {
        if (k0 + 64 < K) {
            int nxt = cur ^ 1;
#pragma unroll
            for (int i = 0; i < BM / 32; ++i)
                gload16(pa + (size_t)(i * 8) * K + k0 + 64, dstA + nxt * ASZ + (i << 9));
#pragma unroll
            for (int i = 0; i < 4; ++i)
                gload16(pb + (size_t)(i * 8) * K + k0 + 64, dstB + nxt * BSZ + (i << 9));
        }
        const short* curA = As + cur * ASZ;
        const short* curB = Bs + cur * BSZ;
#pragma unroll
        for (int ks = 0; ks < 2; ++ks) {
            s16x8 af[MI], bf[4];
#pragma unroll
            for (int mi = 0; mi < MI; ++mi) {
                int row = wr * (BM / 2) + (mi << 4) + lr;
                af[mi] = *reinterpret_cast<const s16x8*>(
                    &curA[(row << 6) + (((ks << 5) + lk8) ^ swz)]);
            }
#pragma unroll
            for (int ni = 0; ni < 4; ++ni) {
                int row = (wc << 6) + (ni << 4) + lr;
                bf[ni] = *reinterpret_cast<const s16x8*>(
                    &curB[(row << 6) + (((ks << 5) + lk8) ^ swz)]);
            }
            __builtin_amdgcn_s_setprio(1);
#pragma unroll
            for (int mi = 0; mi < MI; ++mi)
#pragma unroll
                for (int ni = 0; ni < 4; ++ni)
                    acc[mi][ni] = __builtin_amdgcn_mfma_f32_16x16x32_bf16(
                        af[mi], bf[ni], acc[mi][ni], 0, 0, 0);
            __builtin_amdgcn_s_setprio(0);
        }
        __syncthreads();
        cur ^= 1;
    }

    float bv[4];
#pragma unroll
    for (int ni = 0; ni < 4; ++ni)
        bv[ni] = bias[bn + (wc << 6) + (ni << 4) + lr];

#pragma unroll
    for (int mi = 0; mi < MI; ++mi) {
#pragma unroll
        for (int ni = 0; ni < 4; ++ni) {
            int n = bn + (wc << 6) + (ni << 4) + lr;
#pragma unroll
            for (int r = 0; r < 4; ++r) {
                int m = bm + wr * (BM / 2) + (mi << 4) + r4 + r;
                float v = acc[mi][ni][r] + bv[ni];
                if (RELU) v = fmaxf(v, 0.0f);
                if (RES)  v += R[(size_t)m * N + n];
                if (QKV) {
                    if (bn < 512) {           // block-uniform branch
                        ((short*)Cv)[(size_t)m * 512 + n] = f2bf(v);
                    } else {
                        int hh = (n - 512) >> 6, dd = (n - 512) & 63;
                        int bb = m >> 10, ss = m & 1023;
                        vt[(size_t)((((bb << 2) | hh) << 6) | dd) * 1024 + ss] = f2bf(v);
                    }
                } else if (OBF16) {
                    ((short*)Cv)[(size_t)m * N + n] = f2bf(v);
                } else {
                    ((float*)Cv)[(size_t)m * N + n] = v;
                }
            }
        }
    }
}

// ------------------------------------- fused out-proj + residual + LN2
// 2-phase double-buffered like mgemm. Grid 256 (1 block/CU) -> dbuf is free.
__global__ __launch_bounds__(256) void oproj_ln_kernel(const short* __restrict__ A,
                                                       const short* __restrict__ Bt,
                                                       const float* __restrict__ bias,
                                                       const float* __restrict__ R,
                                                       float* __restrict__ x1,
                                                       short* __restrict__ h2,
                                                       const float* __restrict__ g,
                                                       const float* __restrict__ bb)
{
    constexpr int ASZ = 64 * 64;
    constexpr int BSZ = 256 * 64;
    __shared__ short As[2 * ASZ];
    __shared__ short Bs[2 * BSZ];

    int tid = threadIdx.x;
    int l   = tid & 63;
    int w   = tid >> 6;
    int lr  = l & 15;
    int lk8 = (l >> 4) << 3;
    int r4  = (l >> 4) << 2;
    int bm  = blockIdx.x * 64;

    int scolS = ((l & 7) << 3) ^ ((l >> 3) << 3);
    const short* pa = A  + (size_t)(bm + (w << 4) + (l >> 3)) * 256 + scolS;
    const short* pb = Bt + (size_t)((w << 6) + (l >> 3)) * 256 + scolS;
    short* dstA = As + (w << 10);
    short* dstB = Bs + (w << 12);

    f32x4 acc[16];
#pragma unroll
    for (int ni = 0; ni < 16; ++ni) acc[ni] = (f32x4){0.f, 0.f, 0.f, 0.f};

    int swz = (lr & 7) << 3;

    // prologue
#pragma unroll
    for (int i = 0; i < 2; ++i)
        gload16(pa + (size_t)(i * 8) * 256, dstA + (i << 9));
#pragma unroll
    for (int i = 0; i < 8; ++i)
        gload16(pb + (size_t)(i * 8) * 256, dstB + (i << 9));
    __syncthreads();

    int cur = 0;
    for (int k0 = 0; k0 < 256; k0 += 64) {
        if (k0 + 64 < 256) {
            int nxt = cur ^ 1;
#pragma unroll
            for (int i = 0; i < 2; ++i)
                gload16(pa + (size_t)(i * 8) * 256 + k0 + 64, dstA + nxt * ASZ + (i << 9));
#pragma unroll
            for (int i = 0; i < 8; ++i)
                gload16(pb + (size_t)(i * 8) * 256 + k0 + 64, dstB + nxt * BSZ + (i << 9));
        }
        const short* curA = As + cur * ASZ;
        const short* curB = Bs + cur * BSZ;
#pragma unroll
        for (int ks = 0; ks < 2; ++ks) {
            int arow = (w << 4) + lr;
            s16x8 af = *reinterpret_cast<const s16x8*>(
                &curA[(arow << 6) + (((ks << 5) + lk8) ^ swz)]);
            __builtin_amdgcn_s_setprio(1);
#pragma unroll
            for (int ni = 0; ni < 16; ++ni) {
                int row = (ni << 4) + lr;
                s16x8 bf = *reinterpret_cast<const s16x8*>(
                    &curB[(row << 6) + (((ks << 5) + lk8) ^ swz)]);
                acc[ni] = __builtin_amdgcn_mfma_f32_16x16x32_bf16(af, bf, acc[ni], 0, 0, 0);
            }
            __builtin_amdgcn_s_setprio(0);
        }
        __syncthreads();
        cur ^= 1;
    }

#pragma unroll
    for (int ni = 0; ni < 16; ++ni) {
        int n = (ni << 4) + lr;
        float bvx = bias[n];
#pragma unroll
        for (int r = 0; r < 4; ++r) {
            int m = bm + (w << 4) + r4 + r;
            acc[ni][r] += bvx + R[(size_t)m * 256 + n];
        }
    }
#pragma unroll
    for (int r = 0; r < 4; ++r) {
        float s = 0.0f;
#pragma unroll
        for (int ni = 0; ni < 16; ++ni) s += acc[ni][r];
        s += __shfl_xor(s, 1); s += __shfl_xor(s, 2);
        s += __shfl_xor(s, 4); s += __shfl_xor(s, 8);
        float mu = s * (1.0f / 256.0f);
        float q = 0.0f;
#pragma unroll
        for (int ni = 0; ni < 16; ++ni) {
            float d = acc[ni][r] - mu;
            q += d * d;
        }
        q += __shfl_xor(q, 1); q += __shfl_xor(q, 2);
        q += __shfl_xor(q, 4); q += __shfl_xor(q, 8);
        float rstd = rsqrtf(q * (1.0f / 256.0f) + 1e-5f);

        int m = bm + (w << 4) + r4 + r;
#pragma unroll
        for (int ni = 0; ni < 16; ++ni) {
            int n = (ni << 4) + lr;
            float v = acc[ni][r];
            x1[(size_t)m * 256 + n] = v;
            h2[(size_t)m * 256 + n] = f2bf((v - mu) * rstd * g[n] + bb[n]);
        }
    }
}

// ---------------------------------------------------------------- Attention
// Swapped-QK^T flash attention, KVBLK=64, 2-phase dbuf staging. UNPAIRED:
// grid 1024 (4 blocks/CU resident). Balance: qt = t ^ (bit5(rest)?15:0) --
// under mod-32 or mod-256 round-robin CU assignment, each CU's 4 blocks sum
// to 34 iters. XCD grouping: all blocks of (b,h) land on xcd = bh&7.
// Softmax in-register + defer-max (skip O-rescale unless max grew > 8).
__global__ __launch_bounds__(256, 4) void attn_kernel(const short* __restrict__ qk,
                                                      const short* __restrict__ vt,
                                                      short* __restrict__ o)
{
    __shared__ short Ks[2][64 * 64];
    __shared__ short Vs[2][64 * 64];

    int bid  = blockIdx.x;
    int xcd  = bid & 7;
    int rest = bid >> 3;             // 0..127
    int tq   = rest & 15;
    int flip = (rest >> 5) & 1;
    int qt   = flip ? 15 - tq : tq;
    int bhg  = rest >> 4;            // 0..7
    int bh   = (bhg << 3) | xcd;
    int b = bh >> 2, h = bh & 3;

    int tid = threadIdx.x;
    int l   = tid & 63;
    int w   = tid >> 6;
    int lr  = l & 15;
    int g   = l >> 4;
    int lk8 = g << 3;
    int w16 = w << 4;

    int srow = (w << 3) + (l >> 3);
    int scol = ((l & 7) << 3) ^ (((l >> 3) & 7) << 3);
    const short* kgp = qk + (size_t)(b * 1024 + srow) * 512 + 256 + h * 64 + scol;
    const short* vgp = vt + (size_t)((bh << 6) + srow) * 1024 + scol;
    short* dstK = &Ks[0][(w << 3) * 64];
    short* dstV = &Vs[0][(w << 3) * 64];
    const int BUFS = 64 * 64;

    const float SC = 0.125f * 1.44269504088896f;   // 1/sqrt(D) * log2(e)
    int rsw = (lr & 7) << 3;

    // Q fragments straight from global
    const short* qrow = qk + (size_t)(b * 1024 + qt * 64 + w16 + lr) * 512 + h * 64;
    s16x8 qf[2];
    qf[0] = *reinterpret_cast<const s16x8*>(qrow + lk8);
    qf[1] = *reinterpret_cast<const s16x8*>(qrow + 32 + lk8);

    // prologue: stage kt=0 into half 0
#pragma unroll
    for (int i = 0; i < 2; ++i) {
        gload16(kgp + (size_t)(i * 32) * 512, dstK + (i << 11));
        gload16(vgp + (size_t)(i * 32) * 1024, dstV + (i << 11));
    }
    __syncthreads();

    float m = -1e30f, lsum = 0.0f;
    f32x4 oacc[4];
#pragma unroll
    for (int dt = 0; dt < 4; ++dt) oacc[dt] = (f32x4){0.f, 0.f, 0.f, 0.f};
    int qglob = qt * 64 + w16 + lr;
    int cur = 0;

    for (int kt = 0; kt <= qt; ++kt) {
        // ---- issue next tile's loads (hide under this iter's compute) ----
        if (kt < qt) {
            int nxt = cur ^ 1;
#pragma unroll
            for (int i = 0; i < 2; ++i) {
                gload16(kgp + (size_t)((kt + 1) * 64 + i * 32) * 512,
                        dstK + nxt * BUFS + (i << 11));
                gload16(vgp + (size_t)(i * 32) * 1024 + (kt + 1) * 64,
                        dstV + nxt * BUFS + (i << 11));
            }
        }

        // ---- S^T = K Q^T ----
        f32x4 s[4];
#pragma unroll
        for (int jt = 0; jt < 4; ++jt) s[jt] = (f32x4){0.f, 0.f, 0.f, 0.f};
        __builtin_amdgcn_s_setprio(1);
#pragma unroll
        for (int ks = 0; ks < 2; ++ks) {
#pragma unroll
            for (int jt = 0; jt < 4; ++jt) {
                int row = jt * 16 + lr;
                s16x8 kf = *reinterpret_cast<const s16x8*>(
                    &Ks[cur][(row << 6) + ((32 * ks + lk8) ^ rsw)]);
                s[jt] = __builtin_amdgcn_mfma_f32_16x16x32_bf16(kf, qf[ks], s[jt], 0, 0, 0);
            }
        }
        __builtin_amdgcn_s_setprio(0);
#pragma unroll
        for (int jt = 0; jt < 4; ++jt)
#pragma unroll
            for (int r = 0; r < 4; ++r) s[jt][r] *= SC;

        if (kt == qt) {              // causal mask on diagonal tile
#pragma unroll
            for (int jt = 0; jt < 4; ++jt) {
                int kb = kt * 64 + jt * 16 + (g << 2);
#pragma unroll
                for (int r = 0; r < 4; ++r)
                    if (kb + r > qglob) s[jt][r] = -1e30f;
            }
        }

        // ---- in-register online softmax with defer-max (THR=8, base-2) ----
        float rm = fmaxf(fmaxf(s[0][0], s[0][1]), fmaxf(s[0][2], s[0][3]));
#pragma unroll
        for (int jt = 1; jt < 4; ++jt)
            rm = fmaxf(rm, fmaxf(fmaxf(s[jt][0], s[jt][1]), fmaxf(s[jt][2], s[jt][3])));
        rm = fmaxf(rm, __shfl_xor(rm, 16));
        rm = fmaxf(rm, __shfl_xor(rm, 32));
        bool big = __any(rm > m + 8.0f);
        float fct = 1.0f;
        if (big) {
            float mn = fmaxf(m, rm);
            fct = exp2f(m - mn);
            m = mn;
        }
        float ps = 0.0f;
#pragma unroll
        for (int jt = 0; jt < 4; ++jt)
#pragma unroll
            for (int r = 0; r < 4; ++r) {
                float p = exp2f(s[jt][r] - m);
                s[jt][r] = p;
                ps += p;
            }
        ps += __shfl_xor(ps, 16);
        ps += __shfl_xor(ps, 32);
        lsum = lsum * fct + ps;

        int cpk[4][2];
#pragma unroll
        for (int jt = 0; jt < 4; ++jt) {
            cpk[jt][0] = cvt_pk_bf16(s[jt][0], s[jt][1]);
            cpk[jt][1] = cvt_pk_bf16(s[jt][2], s[jt][3]);
        }

        if (big) {
#pragma unroll
            for (int r = 0; r < 4; ++r) {
                float f4 = __shfl(fct, 4 * g + r);
#pragma unroll
                for (int dt = 0; dt < 4; ++dt) oacc[dt][r] *= f4;
            }
        }

        // ---- O += P V ----
#pragma unroll
        for (int ks = 0; ks < 2; ++ks) {
            int a0 = cpk[2 * ks][0],     a1 = cpk[2 * ks][1];
            int b0 = cpk[2 * ks + 1][0], b1 = cpk[2 * ks + 1][1];
            swap32(a0, b0); swap32(a1, b1);
            swap16(a0, b0); swap16(a1, b1);
            union { int i[4]; s16x8 v; } fr;
            fr.i[0] = a0; fr.i[1] = a1; fr.i[2] = b0; fr.i[3] = b1;
            __builtin_amdgcn_s_setprio(1);
#pragma unroll
            for (int dt = 0; dt < 4; ++dt) {
                int row = dt * 16 + lr;
                s16x8 vf = *reinterpret_cast<const s16x8*>(
                    &Vs[cur][(row << 6) + ((32 * ks + lk8) ^ rsw)]);
                oacc[dt] = __builtin_amdgcn_mfma_f32_16x16x32_bf16(fr.v, vf, oacc[dt], 0, 0, 0);
            }
            __builtin_amdgcn_s_setprio(0);
        }

        if (kt < qt) {
            __syncthreads();         // publishes stage(kt+1); drain overlapped
            cur ^= 1;
        }
    }

    // ---- finalize: O[q=4g+r][d=16dt+lr] /= lsum[q], store bf16 ----
#pragma unroll
    for (int r = 0; r < 4; ++r) {
        float lv  = __shfl(lsum, 4 * g + r);
        float inv = 1.0f / lv;
        short* orow = o + (size_t)(b * 1024 + qt * 64 + w16 + 4 * g + r) * 256 + h * 64;
#pragma unroll
        for (int dt = 0; dt < 4; ++dt)
            orow[dt * 16 + lr] = f2bf(oacc[dt][r] * inv);
    }
}

// ---------------------------------------------------------------- launch
extern "C" void kernel_launch(void* const* d_in, const int* in_sizes, int n_in,
                              void* d_out, int out_size, void* d_ws, size_t ws_size,
                              hipStream_t stream)
{
    const float* x      = (const float*)d_in[0];
    const float* qkv_w  = (const float*)d_in[1];
    const float* qkv_b  = (const float*)d_in[2];
    const float* out_w  = (const float*)d_in[3];
    const float* out_b  = (const float*)d_in[4];
    const float* fc_w   = (const float*)d_in[5];
    const float* fc_b   = (const float*)d_in[6];
    const float* proj_w = (const float*)d_in[7];
    const float* proj_b = (const float*)d_in[8];
    const float* ln1_g  = (const float*)d_in[9];
    const float* ln1_b  = (const float*)d_in[10];
    const float* ln2_g  = (const float*)d_in[11];
    const float* ln2_b  = (const float*)d_in[12];
    float* out = (float*)d_out;

    short* ws = (short*)d_ws;
    short* wt_qkv  = ws;                     // [768][256]
    short* wt_out  = ws + 196608;            // [256][256]
    short* wt_fc   = ws + 262144;            // [1024][256]
    short* wt_proj = ws + 524288;            // [256][1024]
    short* bufA    = ws + 786432;            // [T,256] bf16 (h / o / h2)
    short* qk_buf  = ws + 4980736;           // [T,512] bf16 (q,k)
    short* vt_buf  = ws + 13369344;          // [64][64][1024] bf16 (V^T per bh)
    short* h3_buf  = ws + 4980736;           // [T,1024] overlays qk+vt (dead)

    dim3 blk(256);

    // 0. weight convert+transpose
    wconv_all_kernel<<<dim3(192), blk, 0, stream>>>(
        qkv_w, out_w, fc_w, proj_w, wt_qkv, wt_out, wt_fc, wt_proj);
    // 1. h = LN1(x)
    ln_kernel<<<dim3(4096), blk, 0, stream>>>(x, ln1_g, ln1_b, bufA);
    // 2. qkv = h @ qkv_w + qkv_b   -> qk_buf + vt_buf (V transposed at source)
    mgemm_kernel<0, 0, 1, 128, 1><<<dim3(6, 128), blk, 0, stream>>>(
        bufA, wt_qkv, qkv_b, nullptr, qk_buf, vt_buf, 768, 256);
    // 3. o = attention(qk, vt)
    attn_kernel<<<dim3(1024), blk, 0, stream>>>(qk_buf, vt_buf, bufA);
    // 4. x1 = x + o@out_w+out_b -> d_out ; h2 = LN2(x1) -> bufA  (fused)
    oproj_ln_kernel<<<dim3(256), blk, 0, stream>>>(
        bufA, wt_out, out_b, x, out, bufA, ln2_g, ln2_b);
    // 5. h3 = relu(h2 @ fc_w + fc_b)
    mgemm_kernel<1, 0, 1, 128, 0><<<dim3(8, 128), blk, 0, stream>>>(
        bufA, wt_fc, fc_b, nullptr, h3_buf, nullptr, 1024, 256);
    // 6. out = x1 + h3 @ proj_w + proj_b (in-place residual on d_out)
    mgemm_kernel<0, 1, 0, 64, 0><<<dim3(2, 256), blk, 0, stream>>>(
        h3_buf, wt_proj, proj_b, out, out, nullptr, 256, 1024);
}

// Round 8
// 124.917 us; speedup vs baseline: 1.0591x; 1.0591x over previous
//
#include <hip/hip_runtime.h>
#include <cstdint>

// Transformer block: B=16, S=1024, E=256, H=4, D=64. fp32 in/out, bf16 compute.
// T = B*S = 16384 tokens.
//
//  0. Wt    = transpose+bf16(all weights)      -> ws
//  1. h     = LN1(x)                    bf16   -> bufA
//  2. qkv   = h @ qkv_w + qkv_b         bf16   -> qk_buf [T,512] + vt_buf [BH,64,1024]
//  3. o     = causal_attn(qk, vt)       bf16   -> bufA   (paired, KVBLK=128, dbuf)
//  4. x1,h2 = fused(x + o@out_w+b, LN2) f32,bf16 -> d_out, bufA
//  5. h3    = relu(h2 @ fc_w + b)       bf16   -> bufB (overlays qk/vt)
//  6. out   = x1 + h3 @ proj_w + b      fp32   -> d_out
// GEMMs: round-6 single-buffer structure (dbuf regressed occupancy: m132 trap).

using f32x4 = __attribute__((ext_vector_type(4))) float;
using s16x8 = __attribute__((ext_vector_type(8))) short;
using s16x4 = __attribute__((ext_vector_type(4))) short;

__device__ inline short f2bf(float f) {
    union { float f; unsigned u; } v{f};
    unsigned r = (v.u + 0x7FFFu + ((v.u >> 16) & 1u)) >> 16;   // RNE
    return (short)r;
}

__device__ inline int cvt_pk_bf16(float lo, float hi) {
    int d;
    asm("v_cvt_pk_bf16_f32 %0, %1, %2" : "=v"(d) : "v"(lo), "v"(hi));
    return d;
}
__device__ inline void swap32(int& a, int& b) {
    asm("v_permlane32_swap_b32 %0, %1" : "+v"(a), "+v"(b));
}
__device__ inline void swap16(int& a, int& b) {
    asm("v_permlane16_swap_b32 %0, %1" : "+v"(a), "+v"(b));
}

__device__ inline void gload16(const void* g, void* l) {
    __builtin_amdgcn_global_load_lds(
        (const __attribute__((address_space(1))) void*)g,
        (__attribute__((address_space(3))) void*)l, 16, 0, 0);
}

// ------------------------------------------------ weight fp32->bf16 transpose
__global__ __launch_bounds__(256) void wconv_all_kernel(
    const float* __restrict__ qkv_w, const float* __restrict__ out_w,
    const float* __restrict__ fc_w,  const float* __restrict__ proj_w,
    short* __restrict__ wt_qkv, short* __restrict__ wt_out,
    short* __restrict__ wt_fc,  short* __restrict__ wt_proj)
{
    __shared__ short T[64][65];
    int id = blockIdx.x;
    const float* W; short* Wt; int K, N, nt, kt;
    if (id < 48)       { W = qkv_w;  Wt = wt_qkv;  K = 256;  N = 768;  nt = id % 12;        kt = id / 12; }
    else if (id < 64)  { W = out_w;  Wt = wt_out;  K = 256;  N = 256;  nt = (id - 48) & 3;  kt = (id - 48) >> 2; }
    else if (id < 128) { W = fc_w;   Wt = wt_fc;   K = 256;  N = 1024; nt = (id - 64) & 15; kt = (id - 64) >> 4; }
    else               { W = proj_w; Wt = wt_proj; K = 1024; N = 256;  nt = (id - 128) & 3; kt = (id - 128) >> 2; }
    int n0 = nt * 64, k0 = kt * 64;

    int tid = threadIdx.x;
    int r  = tid >> 2;
    int c  = (tid & 3) << 4;

    const float* src = W + (size_t)(k0 + r) * N + n0 + c;
#pragma unroll
    for (int u = 0; u < 4; ++u) {
        float4 v = *reinterpret_cast<const float4*>(src + u * 4);
        T[r][c + u * 4 + 0] = f2bf(v.x);
        T[r][c + u * 4 + 1] = f2bf(v.y);
        T[r][c + u * 4 + 2] = f2bf(v.z);
        T[r][c + u * 4 + 3] = f2bf(v.w);
    }
    __syncthreads();
    s16x8 o0, o1;
#pragma unroll
    for (int j = 0; j < 8; ++j) { o0[j] = T[c + j][r]; o1[j] = T[c + 8 + j][r]; }
    short* dst = Wt + (size_t)(n0 + r) * K + k0 + c;
    *reinterpret_cast<s16x8*>(dst)     = o0;
    *reinterpret_cast<s16x8*>(dst + 8) = o1;
}

// ---------------------------------------------------------------- LayerNorm
__global__ __launch_bounds__(256) void ln_kernel(const float* __restrict__ x,
                                                 const float* __restrict__ gamma,
                                                 const float* __restrict__ beta,
                                                 short* __restrict__ out)
{
    int tid  = threadIdx.x;
    int lane = tid & 63;
    int row  = blockIdx.x * 4 + (tid >> 6);
    const float* xr = x + (size_t)row * 256;
    float4 v = *reinterpret_cast<const float4*>(xr + lane * 4);

    float s = v.x + v.y + v.z + v.w;
#pragma unroll
    for (int o = 32; o >= 1; o >>= 1) s += __shfl_xor(s, o);
    float mu = s * (1.0f / 256.0f);

    float dx = v.x - mu, dy = v.y - mu, dz = v.z - mu, dw = v.w - mu;
    float q = dx * dx + dy * dy + dz * dz + dw * dw;
#pragma unroll
    for (int o = 32; o >= 1; o >>= 1) q += __shfl_xor(q, o);
    float rstd = rsqrtf(q * (1.0f / 256.0f) + 1e-5f);

    float4 gv = *reinterpret_cast<const float4*>(gamma + lane * 4);
    float4 bv = *reinterpret_cast<const float4*>(beta + lane * 4);
    s16x4 ov;
    ov[0] = f2bf(dx * rstd * gv.x + bv.x);
    ov[1] = f2bf(dy * rstd * gv.y + bv.y);
    ov[2] = f2bf(dz * rstd * gv.z + bv.z);
    ov[3] = f2bf(dw * rstd * gv.w + bv.w);
    *reinterpret_cast<s16x4*>(out + (size_t)row * 256 + lane * 4) = ov;
}

// ---------------------------------------------------------------- MFMA GEMM
// Round-6 single-buffer structure. QKV=1: q,k -> qk_buf stride 512;
// v -> vt_buf [bh][d][s] (V transposed at the source).
template <int RELU, int RES, int OBF16, int BM, int QKV>
__global__ __launch_bounds__(256) void mgemm_kernel(const short* __restrict__ A,
                                                    const short* __restrict__ Bt,
                                                    const float* __restrict__ bias,
                                                    const float* __restrict__ R,
                                                    void* __restrict__ Cv,
                                                    short* __restrict__ vt,
                                                    int N, int K)
{
    constexpr int MI = BM / 32;
    __shared__ short As[BM * 64];
    __shared__ short Bs[128 * 64];

    int tid = threadIdx.x;
    int l   = tid & 63;
    int w   = tid >> 6;
    int lr  = l & 15;
    int lk8 = (l >> 4) << 3;
    int r4  = (l >> 4) << 2;
    int wr  = w >> 1, wc = w & 1;
    int bn  = blockIdx.x * 128, bm = blockIdx.y * BM;

    int scolS = ((l & 7) << 3) ^ ((l >> 3) << 3);
    int srowA = w * (BM / 4) + (l >> 3);
    int srowB = (w << 5) + (l >> 3);
    const short* pa = A  + (size_t)(bm + srowA) * K + scolS;
    const short* pb = Bt + (size_t)(bn + srowB) * K + scolS;
    short* dstA = As + w * (BM / 4) * 64;
    short* dstB = Bs + (w << 11);

    f32x4 acc[MI][4];
#pragma unroll
    for (int mi = 0; mi < MI; ++mi)
#pragma unroll
        for (int ni = 0; ni < 4; ++ni) acc[mi][ni] = (f32x4){0.f, 0.f, 0.f, 0.f};

    int swz = (lr & 7) << 3;

    for (int k0 = 0; k0 < K; k0 += 64) {
        __syncthreads();
#pragma unroll
        for (int i = 0; i < BM / 32; ++i)
            gload16(pa + (size_t)(i * 8) * K + k0, dstA + (i << 9));
#pragma unroll
        for (int i = 0; i < 4; ++i)
            gload16(pb + (size_t)(i * 8) * K + k0, dstB + (i << 9));
        __syncthreads();

#pragma unroll
        for (int ks = 0; ks < 2; ++ks) {
            s16x8 af[MI], bf[4];
#pragma unroll
            for (int mi = 0; mi < MI; ++mi) {
                int row = wr * (BM / 2) + (mi << 4) + lr;
                af[mi] = *reinterpret_cast<const s16x8*>(
                    &As[(row << 6) + (((ks << 5) + lk8) ^ swz)]);
            }
#pragma unroll
            for (int ni = 0; ni < 4; ++ni) {
                int row = (wc << 6) + (ni << 4) + lr;
                bf[ni] = *reinterpret_cast<const s16x8*>(
                    &Bs[(row << 6) + (((ks << 5) + lk8) ^ swz)]);
            }
#pragma unroll
            for (int mi = 0; mi < MI; ++mi)
#pragma unroll
                for (int ni = 0; ni < 4; ++ni)
                    acc[mi][ni] = __builtin_amdgcn_mfma_f32_16x16x32_bf16(
                        af[mi], bf[ni], acc[mi][ni], 0, 0, 0);
        }
    }

    float bv[4];
#pragma unroll
    for (int ni = 0; ni < 4; ++ni)
        bv[ni] = bias[bn + (wc << 6) + (ni << 4) + lr];

#pragma unroll
    for (int mi = 0; mi < MI; ++mi) {
#pragma unroll
        for (int ni = 0; ni < 4; ++ni) {
            int n = bn + (wc << 6) + (ni << 4) + lr;
#pragma unroll
            for (int r = 0; r < 4; ++r) {
                int m = bm + wr * (BM / 2) + (mi << 4) + r4 + r;
                float v = acc[mi][ni][r] + bv[ni];
                if (RELU) v = fmaxf(v, 0.0f);
                if (RES)  v += R[(size_t)m * N + n];
                if (QKV) {
                    if (bn < 512) {           // block-uniform branch
                        ((short*)Cv)[(size_t)m * 512 + n] = f2bf(v);
                    } else {
                        int hh = (n - 512) >> 6, dd = (n - 512) & 63;
                        int bb = m >> 10, ss = m & 1023;
                        vt[(size_t)((((bb << 2) | hh) << 6) | dd) * 1024 + ss] = f2bf(v);
                    }
                } else if (OBF16) {
                    ((short*)Cv)[(size_t)m * N + n] = f2bf(v);
                } else {
                    ((float*)Cv)[(size_t)m * N + n] = v;
                }
            }
        }
    }
}

// ------------------------------------- fused out-proj + residual + LN2
// Round-6 single-buffer structure.
__global__ __launch_bounds__(256) void oproj_ln_kernel(const short* __restrict__ A,
                                                       const short* __restrict__ Bt,
                                                       const float* __restrict__ bias,
                                                       const float* __restrict__ R,
                                                       float* __restrict__ x1,
                                                       short* __restrict__ h2,
                                                       const float* __restrict__ g,
                                                       const float* __restrict__ bb)
{
    __shared__ short As[64 * 64];
    __shared__ short Bs[256 * 64];

    int tid = threadIdx.x;
    int l   = tid & 63;
    int w   = tid >> 6;
    int lr  = l & 15;
    int lk8 = (l >> 4) << 3;
    int r4  = (l >> 4) << 2;
    int bm  = blockIdx.x * 64;

    int scolS = ((l & 7) << 3) ^ ((l >> 3) << 3);
    const short* pa = A  + (size_t)(bm + (w << 4) + (l >> 3)) * 256 + scolS;
    const short* pb = Bt + (size_t)((w << 6) + (l >> 3)) * 256 + scolS;
    short* dstA = As + (w << 10);
    short* dstB = Bs + (w << 12);

    f32x4 acc[16];
#pragma unroll
    for (int ni = 0; ni < 16; ++ni) acc[ni] = (f32x4){0.f, 0.f, 0.f, 0.f};

    int swz = (lr & 7) << 3;

    for (int k0 = 0; k0 < 256; k0 += 64) {
        __syncthreads();
#pragma unroll
        for (int i = 0; i < 2; ++i)
            gload16(pa + (size_t)(i * 8) * 256 + k0, dstA + (i << 9));
#pragma unroll
        for (int i = 0; i < 8; ++i)
            gload16(pb + (size_t)(i * 8) * 256 + k0, dstB + (i << 9));
        __syncthreads();

#pragma unroll
        for (int ks = 0; ks < 2; ++ks) {
            int arow = (w << 4) + lr;
            s16x8 af = *reinterpret_cast<const s16x8*>(
                &As[(arow << 6) + (((ks << 5) + lk8) ^ swz)]);
#pragma unroll
            for (int ni = 0; ni < 16; ++ni) {
                int row = (ni << 4) + lr;
                s16x8 bf = *reinterpret_cast<const s16x8*>(
                    &Bs[(row << 6) + (((ks << 5) + lk8) ^ swz)]);
                acc[ni] = __builtin_amdgcn_mfma_f32_16x16x32_bf16(af, bf, acc[ni], 0, 0, 0);
            }
        }
    }

#pragma unroll
    for (int ni = 0; ni < 16; ++ni) {
        int n = (ni << 4) + lr;
        float bvx = bias[n];
#pragma unroll
        for (int r = 0; r < 4; ++r) {
            int m = bm + (w << 4) + r4 + r;
            acc[ni][r] += bvx + R[(size_t)m * 256 + n];
        }
    }
#pragma unroll
    for (int r = 0; r < 4; ++r) {
        float s = 0.0f;
#pragma unroll
        for (int ni = 0; ni < 16; ++ni) s += acc[ni][r];
        s += __shfl_xor(s, 1); s += __shfl_xor(s, 2);
        s += __shfl_xor(s, 4); s += __shfl_xor(s, 8);
        float mu = s * (1.0f / 256.0f);
        float q = 0.0f;
#pragma unroll
        for (int ni = 0; ni < 16; ++ni) {
            float d = acc[ni][r] - mu;
            q += d * d;
        }
        q += __shfl_xor(q, 1); q += __shfl_xor(q, 2);
        q += __shfl_xor(q, 4); q += __shfl_xor(q, 8);
        float rstd = rsqrtf(q * (1.0f / 256.0f) + 1e-5f);

        int m = bm + (w << 4) + r4 + r;
#pragma unroll
        for (int ni = 0; ni < 16; ++ni) {
            int n = (ni << 4) + lr;
            float v = acc[ni][r];
            x1[(size_t)m * 256 + n] = v;
            h2[(size_t)m * 256 + n] = f2bf((v - mu) * rstd * g[n] + bb[n]);
        }
    }
}

// ---------------------------------------------------------------- Attention
// Swapped-QK^T flash attention, KVBLK=128, PAIRED q-tiles (pair, 15-pair):
// 9 kv-iters per side-pair sum -> balanced by construction, independent of
// dispatch->CU mapping. 2-phase dbuf staging via global_load_lds (linear
// dest + pre-swizzled source); V^T pre-transposed by the qkv GEMM.
// Softmax fully in-register (lane owns q = lane&15) + defer-max (THR=8,
// base-2); P -> PV A-frags via cvt_pk + permlane swaps (no LDS for P).
// Grid 512 = 8 xcd x 8 pair x 8 bhg; all blocks of one (b,h) share an XCD.
// LDS 64 KB -> exactly 2 blocks/CU for the 512-block grid.
__global__ __launch_bounds__(256, 2) void attn_kernel(const short* __restrict__ qk,
                                                      const short* __restrict__ vt,
                                                      short* __restrict__ o)
{
    constexpr int KSZ = 128 * 64;    // shorts per K buffer [k][d]
    constexpr int VSZ = 64 * 128;    // shorts per V^T buffer [d][k]
    __shared__ short Ks[2 * KSZ];
    __shared__ short Vs[2 * VSZ];

    int bid  = blockIdx.x;
    int xcd  = bid & 7;
    int pair = (bid >> 3) & 7;
    int bhg  = bid >> 6;             // 0..7
    int bh   = (bhg << 3) | xcd;
    int b = bh >> 2, h = bh & 3;

    int tid = threadIdx.x;
    int l   = tid & 63;
    int w   = tid >> 6;
    int lr  = l & 15;
    int g   = l >> 4;
    int lk8 = g << 3;
    int w16 = w << 4;

    // K staging: wave w covers rows w*8 + i*32 + (l>>3), i=0..3 (128 rows)
    int krow0 = (w << 3) + (l >> 3);
    int kscol = ((l & 7) << 3) ^ (((l >> 3) & 7) << 3);
    const short* kgp = qk + (size_t)(b * 1024 + krow0) * 512 + 256 + h * 64 + kscol;
    short* dstK = Ks + (w << 3) * 64;                 // wave-uniform base

    // V staging: wave w covers d-rows w*4 + i*16 + (l>>4), i=0..3 (64 rows),
    // 128-short rows; source col pre-swizzled with (d&7)<<3 (i*16 ≡ 0 mod 8).
    int vrow0 = (w << 2) + (l >> 4);
    int vscol = ((l & 15) << 3) ^ ((((w << 2) + (l >> 4)) & 7) << 3);
    const short* vgp = vt + (size_t)((bh << 6) + vrow0) * 1024 + vscol;
    short* dstV = Vs + (w << 2) * 128;                // wave-uniform base

    const float SC = 0.125f * 1.44269504088896f;      // 1/sqrt(D) * log2(e)
    int rsw = (lr & 7) << 3;

    int cur = 0;
    for (int sel = 0; sel < 2; ++sel) {
        int qt = sel == 0 ? pair : 15 - pair;
        int ntile = qt >> 1;         // last 128-wide kv-tile index

        __syncthreads();             // prior tile's LDS reads complete

        // prologue: stage kt=0 into buffer cur
#pragma unroll
        for (int i = 0; i < 4; ++i) {
            gload16(kgp + (size_t)(i * 32) * 512, dstK + cur * KSZ + i * 32 * 64);
            gload16(vgp + (size_t)(i * 16) * 1024, dstV + cur * VSZ + i * 16 * 128);
        }
        __syncthreads();

        // Q fragments straight from global
        const short* qrow = qk + (size_t)(b * 1024 + qt * 64 + w16 + lr) * 512 + h * 64;
        s16x8 qf[2];
        qf[0] = *reinterpret_cast<const s16x8*>(qrow + lk8);
        qf[1] = *reinterpret_cast<const s16x8*>(qrow + 32 + lk8);

        float m = -1e30f, lsum = 0.0f;
        f32x4 oacc[4];
#pragma unroll
        for (int dt = 0; dt < 4; ++dt) oacc[dt] = (f32x4){0.f, 0.f, 0.f, 0.f};
        int qglob = qt * 64 + w16 + lr;

        for (int kt = 0; kt <= ntile; ++kt) {
            // ---- issue next tile's loads (hide under this iter's compute) ----
            if (kt < ntile) {
                int nxt = cur ^ 1;
#pragma unroll
                for (int i = 0; i < 4; ++i) {
                    gload16(kgp + (size_t)((kt + 1) * 128 + i * 32) * 512,
                            dstK + nxt * KSZ + i * 32 * 64);
                    gload16(vgp + (size_t)(i * 16) * 1024 + (kt + 1) * 128,
                            dstV + nxt * VSZ + i * 16 * 128);
                }
            }

            // ---- S^T = K Q^T : 8 k-tiles x 2 d-slices ----
            f32x4 sv[8];
#pragma unroll
            for (int jt = 0; jt < 8; ++jt) sv[jt] = (f32x4){0.f, 0.f, 0.f, 0.f};
            __builtin_amdgcn_s_setprio(1);
#pragma unroll
            for (int ks = 0; ks < 2; ++ks) {
#pragma unroll
                for (int jt = 0; jt < 8; ++jt) {
                    int row = jt * 16 + lr;
                    s16x8 kf = *reinterpret_cast<const s16x8*>(
                        &Ks[cur * KSZ + (row << 6) + ((32 * ks + lk8) ^ rsw)]);
                    sv[jt] = __builtin_amdgcn_mfma_f32_16x16x32_bf16(kf, qf[ks], sv[jt], 0, 0, 0);
                }
            }
            __builtin_amdgcn_s_setprio(0);
#pragma unroll
            for (int jt = 0; jt < 8; ++jt)
#pragma unroll
                for (int r = 0; r < 4; ++r) sv[jt][r] *= SC;

            if (kt == ntile) {       // causal mask (also masks the over-read
                                     // half-tile when qt is even)
#pragma unroll
                for (int jt = 0; jt < 8; ++jt) {
                    int kb = kt * 128 + jt * 16 + (g << 2);
#pragma unroll
                    for (int r = 0; r < 4; ++r)
                        if (kb + r > qglob) sv[jt][r] = -1e30f;
                }
            }

            // ---- in-register online softmax + defer-max (THR=8, base-2) ----
            float rm = fmaxf(fmaxf(sv[0][0], sv[0][1]), fmaxf(sv[0][2], sv[0][3]));
#pragma unroll
            for (int jt = 1; jt < 8; ++jt)
                rm = fmaxf(rm, fmaxf(fmaxf(sv[jt][0], sv[jt][1]),
                                     fmaxf(sv[jt][2], sv[jt][3])));
            rm = fmaxf(rm, __shfl_xor(rm, 16));
            rm = fmaxf(rm, __shfl_xor(rm, 32));
            bool big = __any(rm > m + 8.0f);
            float fct = 1.0f;
            if (big) {
                float mn = fmaxf(m, rm);
                fct = exp2f(m - mn);
                m = mn;
            }
            float ps = 0.0f;
#pragma unroll
            for (int jt = 0; jt < 8; ++jt)
#pragma unroll
                for (int r = 0; r < 4; ++r) {
                    float p = exp2f(sv[jt][r] - m);
                    sv[jt][r] = p;
                    ps += p;
                }
            ps += __shfl_xor(ps, 16);
            ps += __shfl_xor(ps, 32);
            lsum = lsum * fct + ps;

            int cpk[8][2];
#pragma unroll
            for (int jt = 0; jt < 8; ++jt) {
                cpk[jt][0] = cvt_pk_bf16(sv[jt][0], sv[jt][1]);
                cpk[jt][1] = cvt_pk_bf16(sv[jt][2], sv[jt][3]);
            }

            if (big) {
#pragma unroll
                for (int r = 0; r < 4; ++r) {
                    float f4 = __shfl(fct, 4 * g + r);
#pragma unroll
                    for (int dt = 0; dt < 4; ++dt) oacc[dt][r] *= f4;
                }
            }

            // ---- O += P V : 4 32-k slices ----
#pragma unroll
            for (int ks2 = 0; ks2 < 4; ++ks2) {
                int a0 = cpk[2 * ks2][0],     a1 = cpk[2 * ks2][1];
                int b0 = cpk[2 * ks2 + 1][0], b1 = cpk[2 * ks2 + 1][1];
                swap32(a0, b0); swap32(a1, b1);
                swap16(a0, b0); swap16(a1, b1);
                union { int i[4]; s16x8 v; } fr;
                fr.i[0] = a0; fr.i[1] = a1; fr.i[2] = b0; fr.i[3] = b1;
                __builtin_amdgcn_s_setprio(1);
#pragma unroll
                for (int dt = 0; dt < 4; ++dt) {
                    int row = dt * 16 + lr;
                    s16x8 vf = *reinterpret_cast<const s16x8*>(
                        &Vs[cur * VSZ + (row << 7) + ((32 * ks2 + lk8) ^ rsw)]);
                    oacc[dt] = __builtin_amdgcn_mfma_f32_16x16x32_bf16(fr.v, vf, oacc[dt], 0, 0, 0);
                }
                __builtin_amdgcn_s_setprio(0);
            }

            if (kt < ntile) {
                __syncthreads();     // publishes stage(kt+1); drain overlapped
                cur ^= 1;
            }
        }

        // ---- finalize: O[q=4g+r][d=16dt+lr] /= lsum[q], store bf16 ----
#pragma unroll
        for (int r = 0; r < 4; ++r) {
            float lv  = __shfl(lsum, 4 * g + r);
            float inv = 1.0f / lv;
            short* orow = o + (size_t)(b * 1024 + qt * 64 + w16 + 4 * g + r) * 256 + h * 64;
#pragma unroll
            for (int dt = 0; dt < 4; ++dt)
                orow[dt * 16 + lr] = f2bf(oacc[dt][r] * inv);
        }
    }
}

// ---------------------------------------------------------------- launch
extern "C" void kernel_launch(void* const* d_in, const int* in_sizes, int n_in,
                              void* d_out, int out_size, void* d_ws, size_t ws_size,
                              hipStream_t stream)
{
    const float* x      = (const float*)d_in[0];
    const float* qkv_w  = (const float*)d_in[1];
    const float* qkv_b  = (const float*)d_in[2];
    const float* out_w  = (const float*)d_in[3];
    const float* out_b  = (const float*)d_in[4];
    const float* fc_w   = (const float*)d_in[5];
    const float* fc_b   = (const float*)d_in[6];
    const float* proj_w = (const float*)d_in[7];
    const float* proj_b = (const float*)d_in[8];
    const float* ln1_g  = (const float*)d_in[9];
    const float* ln1_b  = (const float*)d_in[10];
    const float* ln2_g  = (const float*)d_in[11];
    const float* ln2_b  = (const float*)d_in[12];
    float* out = (float*)d_out;

    short* ws = (short*)d_ws;
    short* wt_qkv  = ws;                     // [768][256]
    short* wt_out  = ws + 196608;            // [256][256]
    short* wt_fc   = ws + 262144;            // [1024][256]
    short* wt_proj = ws + 524288;            // [256][1024]
    short* bufA    = ws + 786432;            // [T,256] bf16 (h / o / h2)
    short* qk_buf  = ws + 4980736;           // [T,512] bf16 (q,k)
    short* vt_buf  = ws + 13369344;          // [64][64][1024] bf16 (V^T per bh)
    short* h3_buf  = ws + 4980736;           // [T,1024] overlays qk+vt (dead)

    dim3 blk(256);

    // 0. weight convert+transpose
    wconv_all_kernel<<<dim3(192), blk, 0, stream>>>(
        qkv_w, out_w, fc_w, proj_w, wt_qkv, wt_out, wt_fc, wt_proj);
    // 1. h = LN1(x)
    ln_kernel<<<dim3(4096), blk, 0, stream>>>(x, ln1_g, ln1_b, bufA);
    // 2. qkv = h @ qkv_w + qkv_b   -> qk_buf + vt_buf (V transposed at source)
    mgemm_kernel<0, 0, 1, 128, 1><<<dim3(6, 128), blk, 0, stream>>>(
        bufA, wt_qkv, qkv_b, nullptr, qk_buf, vt_buf, 768, 256);
    // 3. o = attention(qk, vt)  — paired causal tiles, KVBLK=128
    attn_kernel<<<dim3(512), blk, 0, stream>>>(qk_buf, vt_buf, bufA);
    // 4. x1 = x + o@out_w+out_b -> d_out ; h2 = LN2(x1) -> bufA  (fused)
    oproj_ln_kernel<<<dim3(256), blk, 0, stream>>>(
        bufA, wt_out, out_b, x, out, bufA, ln2_g, ln2_b);
    // 5. h3 = relu(h2 @ fc_w + fc_b)
    mgemm_kernel<1, 0, 1, 128, 0><<<dim3(8, 128), blk, 0, stream>>>(
        bufA, wt_fc, fc_b, nullptr, h3_buf, nullptr, 1024, 256);
    // 6. out = x1 + h3 @ proj_w + proj_b (in-place residual on d_out)
    mgemm_kernel<0, 1, 0, 64, 0><<<dim3(2, 256), blk, 0, stream>>>(
        h3_buf, wt_proj, proj_b, out, out, nullptr, 256, 1024);
}

// Round 9
// 119.272 us; speedup vs baseline: 1.1093x; 1.0473x over previous
//
#include <hip/hip_runtime.h>
#include <cstdint>

// Transformer block: B=16, S=1024, E=256, H=4, D=64. fp32 in/out, bf16 compute.
// T = B*S = 16384 tokens.
//
//  0. prep  = wconv(all weights) + LN1(x)      -> ws (one kernel)
//  1. qkv   = h @ qkv_w + qkv_b         bf16   -> qk_buf [T,512] + vt_buf [BH,64,1024]
//  2. o     = causal_attn(qk, vt)       bf16   -> bufA   (32x32 MFMA, QBLK=128)
//  3. x1,h2 = fused(x + o@out_w+b, LN2) f32,bf16 -> d_out, bufA   (dbuf)
//  4. h3    = relu(h2 @ fc_w + b)       bf16   -> h3_buf
//  5. out   = x1 + h3 @ proj_w + b      fp32   -> d_out           (dbuf)

using f32x4  = __attribute__((ext_vector_type(4))) float;
using f32x16 = __attribute__((ext_vector_type(16))) float;
using s16x8  = __attribute__((ext_vector_type(8))) short;
using s16x4  = __attribute__((ext_vector_type(4))) short;

__device__ inline short f2bf(float f) {
    union { float f; unsigned u; } v{f};
    unsigned r = (v.u + 0x7FFFu + ((v.u >> 16) & 1u)) >> 16;   // RNE
    return (short)r;
}

__device__ inline int cvt_pk_bf16(float lo, float hi) {
    int d;
    asm("v_cvt_pk_bf16_f32 %0, %1, %2" : "=v"(d) : "v"(lo), "v"(hi));
    return d;
}
// After: a = {a_lo32, b_lo32}, b = {a_hi32, b_hi32} (verified in r5-r8 kernels)
__device__ inline void swap32(int& a, int& b) {
    asm("v_permlane32_swap_b32 %0, %1" : "+v"(a), "+v"(b));
}

__device__ inline void gload16(const void* g, void* l) {
    __builtin_amdgcn_global_load_lds(
        (const __attribute__((address_space(1))) void*)g,
        (__attribute__((address_space(3))) void*)l, 16, 0, 0);
}

// ------------------------------------------------ prep: weight conv + LN1
// blocks [0,192): weight fp32->bf16 transpose; blocks [192, 4288): LN1.
__global__ __launch_bounds__(256) void prep_kernel(
    const float* __restrict__ qkv_w, const float* __restrict__ out_w,
    const float* __restrict__ fc_w,  const float* __restrict__ proj_w,
    short* __restrict__ wt_qkv, short* __restrict__ wt_out,
    short* __restrict__ wt_fc,  short* __restrict__ wt_proj,
    const float* __restrict__ x, const float* __restrict__ ln1_g,
    const float* __restrict__ ln1_b, short* __restrict__ hout)
{
    __shared__ short T[64][65];
    int id  = blockIdx.x;
    int tid = threadIdx.x;

    if (id < 192) {
        const float* W; short* Wt; int K, N, nt, kt;
        if (id < 48)       { W = qkv_w;  Wt = wt_qkv;  K = 256;  N = 768;  nt = id % 12;        kt = id / 12; }
        else if (id < 64)  { W = out_w;  Wt = wt_out;  K = 256;  N = 256;  nt = (id - 48) & 3;  kt = (id - 48) >> 2; }
        else if (id < 128) { W = fc_w;   Wt = wt_fc;   K = 256;  N = 1024; nt = (id - 64) & 15; kt = (id - 64) >> 4; }
        else               { W = proj_w; Wt = wt_proj; K = 1024; N = 256;  nt = (id - 128) & 3; kt = (id - 128) >> 2; }
        int n0 = nt * 64, k0 = kt * 64;
        int r = tid >> 2, c = (tid & 3) << 4;
        const float* src = W + (size_t)(k0 + r) * N + n0 + c;
#pragma unroll
        for (int u = 0; u < 4; ++u) {
            float4 v = *reinterpret_cast<const float4*>(src + u * 4);
            T[r][c + u * 4 + 0] = f2bf(v.x);
            T[r][c + u * 4 + 1] = f2bf(v.y);
            T[r][c + u * 4 + 2] = f2bf(v.z);
            T[r][c + u * 4 + 3] = f2bf(v.w);
        }
        __syncthreads();
        s16x8 o0, o1;
#pragma unroll
        for (int jj = 0; jj < 8; ++jj) { o0[jj] = T[c + jj][r]; o1[jj] = T[c + 8 + jj][r]; }
        short* dst = Wt + (size_t)(n0 + r) * K + k0 + c;
        *reinterpret_cast<s16x8*>(dst)     = o0;
        *reinterpret_cast<s16x8*>(dst + 8) = o1;
    } else {
        int lane = tid & 63;
        int row  = (id - 192) * 4 + (tid >> 6);
        const float* xr = x + (size_t)row * 256;
        float4 v = *reinterpret_cast<const float4*>(xr + lane * 4);
        float s = v.x + v.y + v.z + v.w;
#pragma unroll
        for (int o2 = 32; o2 >= 1; o2 >>= 1) s += __shfl_xor(s, o2);
        float mu = s * (1.0f / 256.0f);
        float dx = v.x - mu, dy = v.y - mu, dz = v.z - mu, dw = v.w - mu;
        float q = dx * dx + dy * dy + dz * dz + dw * dw;
#pragma unroll
        for (int o2 = 32; o2 >= 1; o2 >>= 1) q += __shfl_xor(q, o2);
        float rstd = rsqrtf(q * (1.0f / 256.0f) + 1e-5f);
        float4 gv = *reinterpret_cast<const float4*>(ln1_g + lane * 4);
        float4 bv = *reinterpret_cast<const float4*>(ln1_b + lane * 4);
        s16x4 ov;
        ov[0] = f2bf(dx * rstd * gv.x + bv.x);
        ov[1] = f2bf(dy * rstd * gv.y + bv.y);
        ov[2] = f2bf(dz * rstd * gv.z + bv.z);
        ov[3] = f2bf(dw * rstd * gv.w + bv.w);
        *reinterpret_cast<s16x4*>(hout + (size_t)row * 256 + lane * 4) = ov;
    }
}

// ---------------------------------------------------------------- MFMA GEMM
// DBUF=0: round-8 single-buffer (2 barriers/iter). DBUF=1: double-buffered
// (stage k+1 before compute k, 1 barrier/iter) — use only where the LDS
// doubling is occupancy-free (proj: grid-capped 2/CU).
template <int RELU, int RES, int OBF16, int BM, int QKV, int DBUF>
__global__ __launch_bounds__(256) void mgemm_kernel(const short* __restrict__ A,
                                                    const short* __restrict__ Bt,
                                                    const float* __restrict__ bias,
                                                    const float* __restrict__ R,
                                                    void* __restrict__ Cv,
                                                    short* __restrict__ vt,
                                                    int N, int K)
{
    constexpr int MI  = BM / 32;
    constexpr int ASZ = BM * 64;
    constexpr int BSZ = 128 * 64;
    __shared__ short As[(1 + DBUF) * ASZ];
    __shared__ short Bs[(1 + DBUF) * BSZ];

    int tid = threadIdx.x;
    int l   = tid & 63;
    int w   = tid >> 6;
    int lr  = l & 15;
    int lk8 = (l >> 4) << 3;
    int r4  = (l >> 4) << 2;
    int wr  = w >> 1, wc = w & 1;
    int bn  = blockIdx.x * 128, bm = blockIdx.y * BM;

    int scolS = ((l & 7) << 3) ^ ((l >> 3) << 3);
    int srowA = w * (BM / 4) + (l >> 3);
    int srowB = (w << 5) + (l >> 3);
    const short* pa = A  + (size_t)(bm + srowA) * K + scolS;
    const short* pb = Bt + (size_t)(bn + srowB) * K + scolS;
    short* dstA = As + w * (BM / 4) * 64;
    short* dstB = Bs + (w << 11);

    f32x4 acc[MI][4];
#pragma unroll
    for (int mi = 0; mi < MI; ++mi)
#pragma unroll
        for (int ni = 0; ni < 4; ++ni) acc[mi][ni] = (f32x4){0.f, 0.f, 0.f, 0.f};

    int swz = (lr & 7) << 3;
    int cur = 0;

    if (DBUF) {   // prologue
#pragma unroll
        for (int i = 0; i < BM / 32; ++i)
            gload16(pa + (size_t)(i * 8) * K, dstA + (i << 9));
#pragma unroll
        for (int i = 0; i < 4; ++i)
            gload16(pb + (size_t)(i * 8) * K, dstB + (i << 9));
        __syncthreads();
    }

    for (int k0 = 0; k0 < K; k0 += 64) {
        if (DBUF) {
            if (k0 + 64 < K) {
                int nxt = cur ^ 1;
#pragma unroll
                for (int i = 0; i < BM / 32; ++i)
                    gload16(pa + (size_t)(i * 8) * K + k0 + 64, dstA + nxt * ASZ + (i << 9));
#pragma unroll
                for (int i = 0; i < 4; ++i)
                    gload16(pb + (size_t)(i * 8) * K + k0 + 64, dstB + nxt * BSZ + (i << 9));
            }
        } else {
            __syncthreads();
#pragma unroll
            for (int i = 0; i < BM / 32; ++i)
                gload16(pa + (size_t)(i * 8) * K + k0, dstA + (i << 9));
#pragma unroll
            for (int i = 0; i < 4; ++i)
                gload16(pb + (size_t)(i * 8) * K + k0, dstB + (i << 9));
            __syncthreads();
        }
        const short* curA = As + cur * ASZ;
        const short* curB = Bs + cur * BSZ;
#pragma unroll
        for (int ks = 0; ks < 2; ++ks) {
            s16x8 af[MI], bf[4];
#pragma unroll
            for (int mi = 0; mi < MI; ++mi) {
                int row = wr * (BM / 2) + (mi << 4) + lr;
                af[mi] = *reinterpret_cast<const s16x8*>(
                    &curA[(row << 6) + (((ks << 5) + lk8) ^ swz)]);
            }
#pragma unroll
            for (int ni = 0; ni < 4; ++ni) {
                int row = (wc << 6) + (ni << 4) + lr;
                bf[ni] = *reinterpret_cast<const s16x8*>(
                    &curB[(row << 6) + (((ks << 5) + lk8) ^ swz)]);
            }
            __builtin_amdgcn_s_setprio(1);
#pragma unroll
            for (int mi = 0; mi < MI; ++mi)
#pragma unroll
                for (int ni = 0; ni < 4; ++ni)
                    acc[mi][ni] = __builtin_amdgcn_mfma_f32_16x16x32_bf16(
                        af[mi], bf[ni], acc[mi][ni], 0, 0, 0);
            __builtin_amdgcn_s_setprio(0);
        }
        if (DBUF) {
            __syncthreads();
            cur ^= 1;
        }
    }

    float bv[4];
#pragma unroll
    for (int ni = 0; ni < 4; ++ni)
        bv[ni] = bias[bn + (wc << 6) + (ni << 4) + lr];

#pragma unroll
    for (int mi = 0; mi < MI; ++mi) {
#pragma unroll
        for (int ni = 0; ni < 4; ++ni) {
            int n = bn + (wc << 6) + (ni << 4) + lr;
#pragma unroll
            for (int r = 0; r < 4; ++r) {
                int m = bm + wr * (BM / 2) + (mi << 4) + r4 + r;
                float v = acc[mi][ni][r] + bv[ni];
                if (RELU) v = fmaxf(v, 0.0f);
                if (RES)  v += R[(size_t)m * N + n];
                if (QKV) {
                    if (bn < 512) {
                        ((short*)Cv)[(size_t)m * 512 + n] = f2bf(v);
                    } else {
                        int hh = (n - 512) >> 6, dd = (n - 512) & 63;
                        int bb = m >> 10, ss = m & 1023;
                        vt[(size_t)((((bb << 2) | hh) << 6) | dd) * 1024 + ss] = f2bf(v);
                    }
                } else if (OBF16) {
                    ((short*)Cv)[(size_t)m * N + n] = f2bf(v);
                } else {
                    ((float*)Cv)[(size_t)m * N + n] = v;
                }
            }
        }
    }
}

// ------------------------------------- fused out-proj + residual + LN2
// Double-buffered (grid 256 = 1 block/CU -> 80 KB LDS is occupancy-free).
__global__ __launch_bounds__(256) void oproj_ln_kernel(const short* __restrict__ A,
                                                       const short* __restrict__ Bt,
                                                       const float* __restrict__ bias,
                                                       const float* __restrict__ R,
                                                       float* __restrict__ x1,
                                                       short* __restrict__ h2,
                                                       const float* __restrict__ g,
                                                       const float* __restrict__ bb)
{
    constexpr int ASZ = 64 * 64;
    constexpr int BSZ = 256 * 64;
    __shared__ short As[2 * ASZ];
    __shared__ short Bs[2 * BSZ];

    int tid = threadIdx.x;
    int l   = tid & 63;
    int w   = tid >> 6;
    int lr  = l & 15;
    int lk8 = (l >> 4) << 3;
    int r4  = (l >> 4) << 2;
    int bm  = blockIdx.x * 64;

    int scolS = ((l & 7) << 3) ^ ((l >> 3) << 3);
    const short* pa = A  + (size_t)(bm + (w << 4) + (l >> 3)) * 256 + scolS;
    const short* pb = Bt + (size_t)((w << 6) + (l >> 3)) * 256 + scolS;
    short* dstA = As + (w << 10);
    short* dstB = Bs + (w << 12);

    f32x4 acc[16];
#pragma unroll
    for (int ni = 0; ni < 16; ++ni) acc[ni] = (f32x4){0.f, 0.f, 0.f, 0.f};

    int swz = (lr & 7) << 3;

    // prologue
#pragma unroll
    for (int i = 0; i < 2; ++i)
        gload16(pa + (size_t)(i * 8) * 256, dstA + (i << 9));
#pragma unroll
    for (int i = 0; i < 8; ++i)
        gload16(pb + (size_t)(i * 8) * 256, dstB + (i << 9));
    __syncthreads();

    int cur = 0;
    for (int k0 = 0; k0 < 256; k0 += 64) {
        if (k0 + 64 < 256) {
            int nxt = cur ^ 1;
#pragma unroll
            for (int i = 0; i < 2; ++i)
                gload16(pa + (size_t)(i * 8) * 256 + k0 + 64, dstA + nxt * ASZ + (i << 9));
#pragma unroll
            for (int i = 0; i < 8; ++i)
                gload16(pb + (size_t)(i * 8) * 256 + k0 + 64, dstB + nxt * BSZ + (i << 9));
        }
        const short* curA = As + cur * ASZ;
        const short* curB = Bs + cur * BSZ;
#pragma unroll
        for (int ks = 0; ks < 2; ++ks) {
            int arow = (w << 4) + lr;
            s16x8 af = *reinterpret_cast<const s16x8*>(
                &curA[(arow << 6) + (((ks << 5) + lk8) ^ swz)]);
            __builtin_amdgcn_s_setprio(1);
#pragma unroll
            for (int ni = 0; ni < 16; ++ni) {
                int row = (ni << 4) + lr;
                s16x8 bf = *reinterpret_cast<const s16x8*>(
                    &curB[(row << 6) + (((ks << 5) + lk8) ^ swz)]);
                acc[ni] = __builtin_amdgcn_mfma_f32_16x16x32_bf16(af, bf, acc[ni], 0, 0, 0);
            }
            __builtin_amdgcn_s_setprio(0);
        }
        __syncthreads();
        cur ^= 1;
    }

#pragma unroll
    for (int ni = 0; ni < 16; ++ni) {
        int n = (ni << 4) + lr;
        float bvx = bias[n];
#pragma unroll
        for (int r = 0; r < 4; ++r) {
            int m = bm + (w << 4) + r4 + r;
            acc[ni][r] += bvx + R[(size_t)m * 256 + n];
        }
    }
#pragma unroll
    for (int r = 0; r < 4; ++r) {
        float s = 0.0f;
#pragma unroll
        for (int ni = 0; ni < 16; ++ni) s += acc[ni][r];
        s += __shfl_xor(s, 1); s += __shfl_xor(s, 2);
        s += __shfl_xor(s, 4); s += __shfl_xor(s, 8);
        float mu = s * (1.0f / 256.0f);
        float q = 0.0f;
#pragma unroll
        for (int ni = 0; ni < 16; ++ni) {
            float d = acc[ni][r] - mu;
            q += d * d;
        }
        q += __shfl_xor(q, 1); q += __shfl_xor(q, 2);
        q += __shfl_xor(q, 4); q += __shfl_xor(q, 8);
        float rstd = rsqrtf(q * (1.0f / 256.0f) + 1e-5f);

        int m = bm + (w << 4) + r4 + r;
#pragma unroll
        for (int ni = 0; ni < 16; ++ni) {
            int n = (ni << 4) + lr;
            float v = acc[ni][r];
            x1[(size_t)m * 256 + n] = v;
            h2[(size_t)m * 256 + n] = f2bf((v - mu) * rstd * g[n] + bb[n]);
        }
    }
}

// ---------------------------------------------------------------- Attention
// 32x32x16 MFMA flash attention (halves LDS operand bytes/FLOP vs 16x16x32 —
// the measured-invariant bottleneck). QBLK=128: 4 waves x 32 q-rows each;
// KVBLK=128, double-buffered staging. Swapped QK^T (S^T = K·Q^T): D-layout
// col = l&31 = q, row(k) = (r&3)+8*(r>>2)+4*(l>>5) -> softmax is in-lane
// (16 values x 4 tiles) + ONE shfl_xor(32). P->PV A-frags via cvt_pk +
// permlane32_swap only. Grid 512 = xcd(8) x bhg(8) x qidx(8); qt order
// {0,1,2,3,7,6,5,4} makes co-resident block pairs (bid, bid+256) sum to a
// constant 9 iterations and share the same (b,h) K/V.
__global__ __launch_bounds__(256, 2) void attn_kernel(const short* __restrict__ qk,
                                                      const short* __restrict__ vt,
                                                      short* __restrict__ o)
{
    constexpr int KSZ = 128 * 64;    // K buffer [k][d]
    constexpr int VSZ = 64 * 128;    // V^T buffer [d][k]
    __shared__ short Ks[2 * KSZ];
    __shared__ short Vs[2 * VSZ];

    int bid  = blockIdx.x;
    int xcd  = bid & 7;
    int j    = bid >> 3;             // 0..63
    int bhg  = j & 7;
    int qidx = j >> 3;               // 0..7
    int qt   = qidx < 4 ? qidx : 11 - qidx;   // {0,1,2,3,7,6,5,4}
    int bh   = (bhg << 3) | xcd;
    int b = bh >> 2, h = bh & 3;

    int tid = threadIdx.x;
    int l   = tid & 63;
    int w   = tid >> 6;              // wave: q-rows [qt*128+32w, +32)
    int lq  = l & 31;                // q col / d col / k row
    int hg  = l >> 5;                // lane half-group

    // staging (same tile shapes as r8)
    int krow0 = (w << 3) + (l >> 3);
    int kscol = ((l & 7) << 3) ^ (((l >> 3) & 7) << 3);
    const short* kgp = qk + (size_t)(b * 1024 + krow0) * 512 + 256 + h * 64 + kscol;
    short* dstK = Ks + (w << 3) * 64;
    int vrow0 = (w << 2) + (l >> 4);
    int vscol = ((l & 15) << 3) ^ ((vrow0 & 7) << 3);
    const short* vgp = vt + (size_t)((bh << 6) + vrow0) * 1024 + vscol;
    short* dstV = Vs + (w << 2) * 128;

    const float SC = 0.125f * 1.44269504088896f;   // 1/sqrt(D) * log2(e)

    // Q fragments (B-operand): q = qt*128+32w+lq; d = 16*ds + 8*hg + b
    const short* qrow = qk + (size_t)(b * 1024 + qt * 128 + (w << 5) + lq) * 512
                        + h * 64 + (hg << 3);
    s16x8 qf[4];
#pragma unroll
    for (int ds = 0; ds < 4; ++ds)
        qf[ds] = *reinterpret_cast<const s16x8*>(qrow + 16 * ds);

    // prologue: stage kt=0 into buffer 0
#pragma unroll
    for (int i = 0; i < 4; ++i) {
        gload16(kgp + (size_t)(i * 32) * 512, dstK + i * 32 * 64);
        gload16(vgp + (size_t)(i * 16) * 1024, dstV + i * 16 * 128);
    }
    __syncthreads();

    float m = -1e30f, lsum = 0.0f;
    f32x16 oacc[2];
#pragma unroll
    for (int dt = 0; dt < 2; ++dt)
#pragma unroll
        for (int r = 0; r < 16; ++r) oacc[dt][r] = 0.0f;
    int qglob = qt * 128 + (w << 5) + lq;
    int cur = 0;
    int niter = qt + 1;

    for (int kt = 0; kt < niter; ++kt) {
        if (kt + 1 < niter) {
            int nxt = cur ^ 1;
#pragma unroll
            for (int i = 0; i < 4; ++i) {
                gload16(kgp + (size_t)((kt + 1) * 128 + i * 32) * 512,
                        dstK + nxt * KSZ + i * 32 * 64);
                gload16(vgp + (size_t)(i * 16) * 1024 + (kt + 1) * 128,
                        dstV + nxt * VSZ + i * 16 * 128);
            }
        }

        // ---- S^T = K Q^T : 4 k-tiles (32 k) x 4 d-slices (16 d) ----
        f32x16 sv[4];
#pragma unroll
        for (int jt = 0; jt < 4; ++jt)
#pragma unroll
            for (int r = 0; r < 16; ++r) sv[jt][r] = 0.0f;
        __builtin_amdgcn_s_setprio(1);
#pragma unroll
        for (int ds = 0; ds < 4; ++ds) {
#pragma unroll
            for (int jt = 0; jt < 4; ++jt) {
                int row = jt * 32 + lq;
                s16x8 kf = *reinterpret_cast<const s16x8*>(
                    &Ks[cur * KSZ + (row << 6) + ((16 * ds + (hg << 3)) ^ ((row & 7) << 3))]);
                sv[jt] = __builtin_amdgcn_mfma_f32_32x32x16_bf16(kf, qf[ds], sv[jt], 0, 0, 0);
            }
        }
        __builtin_amdgcn_s_setprio(0);
#pragma unroll
        for (int jt = 0; jt < 4; ++jt)
#pragma unroll
            for (int r = 0; r < 16; ++r) sv[jt][r] *= SC;

        if (kt == niter - 1) {       // causal mask on diagonal tile
#pragma unroll
            for (int jt = 0; jt < 4; ++jt)
#pragma unroll
                for (int r = 0; r < 16; ++r) {
                    int kg = kt * 128 + jt * 32 + (r & 3) + ((r >> 2) << 3) + (hg << 2);
                    if (kg > qglob) sv[jt][r] = -1e30f;
                }
        }

        // ---- in-register online softmax + defer-max (THR=8, base-2) ----
        float rm = -1e30f;
#pragma unroll
        for (int jt = 0; jt < 4; ++jt)
#pragma unroll
            for (int r = 0; r < 16; ++r) rm = fmaxf(rm, sv[jt][r]);
        rm = fmaxf(rm, __shfl_xor(rm, 32));
        bool big = __any(rm > m + 8.0f);
        float fct = 1.0f;
        if (big) {
            float mn = fmaxf(m, rm);
            fct = exp2f(m - mn);
            m = mn;
        }
        float ps = 0.0f;
#pragma unroll
        for (int jt = 0; jt < 4; ++jt)
#pragma unroll
            for (int r = 0; r < 16; ++r) {
                float p = exp2f(sv[jt][r] - m);
                sv[jt][r] = p;
                ps += p;
            }
        ps += __shfl_xor(ps, 32);
        lsum = lsum * fct + ps;

        if (big) {
#pragma unroll
            for (int r = 0; r < 16; ++r) {
                float f = __shfl(fct, (r & 3) + ((r >> 2) << 3) + (hg << 2));
                oacc[0][r] *= f;
                oacc[1][r] *= f;
            }
        }

        // ---- O += P V : per jt (32 k), build two 16-k A-frags, 4 MFMA ----
#pragma unroll
        for (int jt = 0; jt < 4; ++jt) {
            int x0 = cvt_pk_bf16(sv[jt][0],  sv[jt][1]);
            int x1 = cvt_pk_bf16(sv[jt][2],  sv[jt][3]);
            int y0 = cvt_pk_bf16(sv[jt][4],  sv[jt][5]);
            int y1 = cvt_pk_bf16(sv[jt][6],  sv[jt][7]);
            int z0 = cvt_pk_bf16(sv[jt][8],  sv[jt][9]);
            int z1 = cvt_pk_bf16(sv[jt][10], sv[jt][11]);
            int w0 = cvt_pk_bf16(sv[jt][12], sv[jt][13]);
            int w1 = cvt_pk_bf16(sv[jt][14], sv[jt][15]);
            swap32(x0, y0); swap32(x1, y1);   // -> frag A = [x0,x1,y0,y1]
            swap32(z0, w0); swap32(z1, w1);   // -> frag B = [z0,z1,w0,w1]
            union { int i[4]; s16x8 v; } fA, fB;
            fA.i[0] = x0; fA.i[1] = x1; fA.i[2] = y0; fA.i[3] = y1;
            fB.i[0] = z0; fB.i[1] = z1; fB.i[2] = w0; fB.i[3] = w1;
            __builtin_amdgcn_s_setprio(1);
#pragma unroll
            for (int dt = 0; dt < 2; ++dt) {
                int row = dt * 32 + lq;
                int rs  = (row & 7) << 3;
                s16x8 vfA = *reinterpret_cast<const s16x8*>(
                    &Vs[cur * VSZ + (row << 7) + ((16 * (2 * jt)     + (hg << 3)) ^ rs)]);
                oacc[dt] = __builtin_amdgcn_mfma_f32_32x32x16_bf16(fA.v, vfA, oacc[dt], 0, 0, 0);
                s16x8 vfB = *reinterpret_cast<const s16x8*>(
                    &Vs[cur * VSZ + (row << 7) + ((16 * (2 * jt + 1) + (hg << 3)) ^ rs)]);
                oacc[dt] = __builtin_amdgcn_mfma_f32_32x32x16_bf16(fB.v, vfB, oacc[dt], 0, 0, 0);
            }
            __builtin_amdgcn_s_setprio(0);
        }

        if (kt + 1 < niter) {
            __syncthreads();         // publishes stage(kt+1); drain overlapped
            cur ^= 1;
        }
    }

    // ---- finalize: O[q_r][d = 32dt+lq] /= lsum[q_r], store bf16 ----
#pragma unroll
    for (int r = 0; r < 16; ++r) {
        int qr  = (r & 3) + ((r >> 2) << 3) + (hg << 2);
        float lv  = __shfl(lsum, qr);
        float inv = 1.0f / lv;
        int q = qt * 128 + (w << 5) + qr;
        short* orow = o + (size_t)(b * 1024 + q) * 256 + h * 64;
        orow[lq]      = f2bf(oacc[0][r] * inv);
        orow[32 + lq] = f2bf(oacc[1][r] * inv);
    }
}

// ---------------------------------------------------------------- launch
extern "C" void kernel_launch(void* const* d_in, const int* in_sizes, int n_in,
                              void* d_out, int out_size, void* d_ws, size_t ws_size,
                              hipStream_t stream)
{
    const float* x      = (const float*)d_in[0];
    const float* qkv_w  = (const float*)d_in[1];
    const float* qkv_b  = (const float*)d_in[2];
    const float* out_w  = (const float*)d_in[3];
    const float* out_b  = (const float*)d_in[4];
    const float* fc_w   = (const float*)d_in[5];
    const float* fc_b   = (const float*)d_in[6];
    const float* proj_w = (const float*)d_in[7];
    const float* proj_b = (const float*)d_in[8];
    const float* ln1_g  = (const float*)d_in[9];
    const float* ln1_b  = (const float*)d_in[10];
    const float* ln2_g  = (const float*)d_in[11];
    const float* ln2_b  = (const float*)d_in[12];
    float* out = (float*)d_out;

    short* ws = (short*)d_ws;
    short* wt_qkv  = ws;                     // [768][256]
    short* wt_out  = ws + 196608;            // [256][256]
    short* wt_fc   = ws + 262144;            // [1024][256]
    short* wt_proj = ws + 524288;            // [256][1024]
    short* bufA    = ws + 786432;            // [T,256] bf16 (h / o / h2)
    short* qk_buf  = ws + 4980736;           // [T,512] bf16 (q,k)
    short* vt_buf  = ws + 13369344;          // [64][64][1024] bf16 (V^T per bh)
    short* h3_buf  = ws + 4980736;           // [T,1024] overlays qk+vt (dead)

    dim3 blk(256);

    // 0. weight convert + LN1 (single launch)
    prep_kernel<<<dim3(4288), blk, 0, stream>>>(
        qkv_w, out_w, fc_w, proj_w, wt_qkv, wt_out, wt_fc, wt_proj,
        x, ln1_g, ln1_b, bufA);
    // 1. qkv = h @ qkv_w + qkv_b   -> qk_buf + vt_buf (V transposed at source)
    mgemm_kernel<0, 0, 1, 128, 1, 0><<<dim3(6, 128), blk, 0, stream>>>(
        bufA, wt_qkv, qkv_b, nullptr, qk_buf, vt_buf, 768, 256);
    // 2. o = attention(qk, vt)  — 32x32 MFMA, QBLK=128
    attn_kernel<<<dim3(512), blk, 0, stream>>>(qk_buf, vt_buf, bufA);
    // 3. x1 = x + o@out_w+out_b -> d_out ; h2 = LN2(x1) -> bufA  (fused, dbuf)
    oproj_ln_kernel<<<dim3(256), blk, 0, stream>>>(
        bufA, wt_out, out_b, x, out, bufA, ln2_g, ln2_b);
    // 4. h3 = relu(h2 @ fc_w + fc_b)
    mgemm_kernel<1, 0, 1, 128, 0, 0><<<dim3(8, 128), blk, 0, stream>>>(
        bufA, wt_fc, fc_b, nullptr, h3_buf, nullptr, 1024, 256);
    // 5. out = x1 + h3 @ proj_w + proj_b (in-place residual, dbuf pipeline)
    mgemm_kernel<0, 1, 0, 64, 0, 1><<<dim3(2, 256), blk, 0, stream>>>(
        h3_buf, wt_proj, proj_b, out, out, nullptr, 256, 1024);
}